// Round 11
// baseline (146.252 us; speedup 1.0000x reference)
//
#include <hip/hip_runtime.h>

typedef unsigned short ushort_t;
using short8 = __attribute__((ext_vector_type(8))) short;
using half4  = __attribute__((ext_vector_type(4))) _Float16;
using half8  = __attribute__((ext_vector_type(8))) _Float16;
using f32x4  = __attribute__((ext_vector_type(4))) float;

#define AS1 __attribute__((address_space(1)))
#define AS3 __attribute__((address_space(3)))

// Problem sizes (fixed)
#define B_   8
#define S_   2048
#define D_   1024
#define NIN  (8UL * 2048UL * 1024UL)
#define PARTS 32
#define SROWB 8192UL
#define BATCHB (2048UL * SROWB)

// Per-score-row layout during the pipeline:
//   [0,128)     : 32 f32 partial row sums (one per 64-col block) (gemm -> normalize)
//   [2048,4096) : bf16 X row                                     (cvt -> gemm)
//   [4096,8192) : f16 E row = exp(logits)                        (gemm -> normalize)
// normalize overwrites the whole row with final f32 scores.
// The exact f32 input copy streams through the gemm's idle VMEM slots.

__device__ __forceinline__ ushort_t f2bf(float f) {
    unsigned u = __float_as_uint(f);
    u += 0x7FFFu + ((u >> 16) & 1u);
    return (ushort_t)(u >> 16);
}

// ---------- kernel 1: f32 X -> parked bf16 ----------
__global__ __launch_bounds__(256) void cvt_packed(const float* __restrict__ in,
                                                  char* sc) {
    size_t g = ((size_t)blockIdx.x * 256 + threadIdx.x) * 8;
    const f32x4* p = (const f32x4*)(in + g);
    f32x4 a = p[0], c = p[1];
    short8 r;
    r[0] = (short)f2bf(a.x); r[1] = (short)f2bf(a.y);
    r[2] = (short)f2bf(a.z); r[3] = (short)f2bf(a.w);
    r[4] = (short)f2bf(c.x); r[5] = (short)f2bf(c.y);
    r[6] = (short)f2bf(c.z); r[7] = (short)f2bf(c.w);
    size_t xrow = g >> 10;
    size_t col  = g & 1023;
    char* dst = sc + xrow * SROWB + 2048 + col * 2;
    *(short8*)dst = r;
}

// ---------- kernel 2: symmetric GEMM, 256x256 tiles, ring-2 + embedded copy ----------
// 36 upper-tri tiles/batch (8x8 grid), 288 blocks, 512 threads (8 waves 2x4),
// per-wave 128x64 output = acc[8][4] f32x4.
__global__ __launch_bounds__(512, 2) void gemm_sym7(char* sc,
                                                    const f32x4* xin,
                                                    f32x4* xout) {
    __shared__ __align__(16) ushort_t sA[2][256 * 64];   // 2 x 32 KB
    __shared__ __align__(16) ushort_t sB[2][256 * 64];   // 2 x 32 KB  (128 KB total)

    const int lin = blockIdx.x;
    // bijective XCD swizzle: 288 = 8 * 36
    const int wg  = (lin & 7) * 36 + (lin >> 3);
    const int b   = wg / 36;
    int rem = wg % 36, ti = 0;
    while (rem >= 8 - ti) { rem -= 8 - ti; ++ti; }
    const int tj = ti + rem;
    const int tr = ti * 256, tc = tj * 256;

    char* Sb = sc + (size_t)b * BATCHB;

    const int tid  = threadIdx.x;
    const int lane = tid & 63;
    const int wid  = tid >> 6;            // 0..7
    const int wrow = (wid >> 2) * 128;    // 0,128
    const int wcol = (wid & 3) * 64;      // 0,64,128,192

    const bool docopy = (lin < 256);
    const size_t cbase = (size_t)lin * 512 + tid;   // < 131072 when docopy

    f32x4 acc[8][4] = {};
    f32x4 creg0, creg1;

    const int srow_s = tid >> 3;          // 0..63
    const int cd     = tid & 7;
    const int rsel = lane & 15;
    const int g4   = lane >> 4;           // 0..3

    auto stage = [&](int s, int slot) {
#pragma unroll
        for (int j = 0; j < 4; ++j) {
            const int row = j * 64 + srow_s;
            const int csw = (cd ^ (row & 7)) << 4;
            __builtin_amdgcn_global_load_lds(
                (const AS1 void*)(Sb + (size_t)(tr + row) * SROWB + 2048 + (size_t)s * 128 + csw),
                (AS3 void*)((char*)&sA[slot][0] + j * 8192 + tid * 16), 16, 0, 0);
        }
#pragma unroll
        for (int j = 0; j < 4; ++j) {
            const int row = j * 64 + srow_s;
            const int csw = (cd ^ (row & 7)) << 4;
            __builtin_amdgcn_global_load_lds(
                (const AS1 void*)(Sb + (size_t)(tc + row) * SROWB + 2048 + (size_t)s * 128 + csw),
                (AS3 void*)((char*)&sB[slot][0] + j * 8192 + tid * 16), 16, 0, 0);
        }
    };

    // fragment read of one kk half-slice (48 VGPR live)
    short8 af[8], bfr[4];
    auto readfrags = [&](int slot, int kk) {
        const int cb  = kk * 4 + g4;
#pragma unroll
        for (int m = 0; m < 8; ++m) {
            const int row = wrow + m * 16 + rsel;
            af[m] = *(const short8*)((const char*)&sA[slot][0] + row * 128 + ((cb ^ (row & 7)) << 4));
        }
#pragma unroll
        for (int n = 0; n < 4; ++n) {
            const int row = wcol + n * 16 + rsel;
            bfr[n] = *(const short8*)((const char*)&sB[slot][0] + row * 128 + ((cb ^ (row & 7)) << 4));
        }
    };
    auto mfma32 = [&]() {
#pragma unroll
        for (int m = 0; m < 8; ++m)
#pragma unroll
            for (int n = 0; n < 4; ++n)
                acc[m][n] = __builtin_amdgcn_mfma_f32_16x16x32_bf16(
                    af[m], bfr[n], acc[m][n], 0, 0, 0);
    };

    // prologue: stage slices 0,1 (8 ops each); wait slice 0
    stage(0, 0);
    stage(1, 1);
    asm volatile("s_waitcnt vmcnt(8)" ::: "memory");
    __builtin_amdgcn_s_barrier();

#pragma unroll
    for (int s = 0; s < 16; ++s) {
        const int slot = s & 1;

        // kk=0: read frags, compute
        readfrags(slot, 0);
        asm volatile("s_waitcnt lgkmcnt(0)" ::: "memory");
        __builtin_amdgcn_sched_barrier(0);
        __builtin_amdgcn_s_setprio(1);
        mfma32();
        __builtin_amdgcn_s_setprio(0);

        // kk=1: read frags (must finish before B1), compute after B2
        readfrags(slot, 1);
        asm volatile("s_waitcnt lgkmcnt(0)" ::: "memory");
        __builtin_amdgcn_sched_barrier(0);
        __builtin_amdgcn_s_barrier();        // B1: all waves done reading slot

        if (s + 2 < 16) stage(s + 2, slot);  // overwrite just-read slot (8 ops)

        if (docopy) {
            if (s > 0) {
                xout[cbase + (size_t)(s - 1) * 262144]          = creg0;
                xout[cbase + (size_t)(s - 1) * 262144 + 131072] = creg1;
            }
            creg0 = xin[cbase + (size_t)s * 262144];
            creg1 = xin[cbase + (size_t)s * 262144 + 131072];
        }

        // counted waits: guarantee stage(s+1) landed; newer ops stay in flight
        if (docopy) {
            if (s == 0)       asm volatile("s_waitcnt vmcnt(10)" ::: "memory");
            else if (s == 1)  asm volatile("s_waitcnt vmcnt(14)" ::: "memory");
            else if (s < 14)  asm volatile("s_waitcnt vmcnt(16)" ::: "memory");
            else if (s == 14) asm volatile("s_waitcnt vmcnt(8)"  ::: "memory");
        } else {
            if (s + 2 < 16)   asm volatile("s_waitcnt vmcnt(8)"  ::: "memory");
            else if (s == 14) asm volatile("s_waitcnt vmcnt(0)"  ::: "memory");
        }
        __builtin_amdgcn_s_barrier();        // B2: everyone's slice s+1 resident

        __builtin_amdgcn_s_setprio(1);
        mfma32();                            // kk=1 compute, overlaps in-flight VMEM
        __builtin_amdgcn_s_setprio(0);
    }

    if (docopy) {
        xout[cbase + 15UL * 262144]          = creg0;   // compiler inserts vmcnt for creg deps
        xout[cbase + 15UL * 262144 + 131072] = creg1;
    }

    // ---------------- epilogue ----------------
    const float scale = 1.0f / 2048.0f;
    const int r0 = (lane >> 4) * 4;
    const int c0 = lane & 15;

#pragma unroll
    for (int m = 0; m < 8; ++m)
#pragma unroll
        for (int n = 0; n < 4; ++n)
#pragma unroll
            for (int rr = 0; rr < 4; ++rr)
                acc[m][n][rr] = __expf(acc[m][n][rr] * scale);

    // direct E writes: rows tr+wrow+m*16+r0+rr, cols tc+wcol+n*16+c0
#pragma unroll
    for (int m = 0; m < 8; ++m) {
#pragma unroll
        for (int n = 0; n < 4; ++n) {
            char* dbase = Sb + (size_t)(tr + wrow + m * 16 + r0) * SROWB + 4096
                             + (size_t)(tc + wcol + n * 16 + c0) * 2;
#pragma unroll
            for (int rr = 0; rr < 4; ++rr)
                *(_Float16*)(dbase + (size_t)rr * SROWB) = (_Float16)acc[m][n][rr];
        }
    }

    // direct row sums -> own-row slot tj*4 + (wid&3)  (64-col block sums)
#pragma unroll
    for (int m = 0; m < 8; ++m) {
#pragma unroll
        for (int rr = 0; rr < 4; ++rr) {
            float s = (acc[m][0][rr] + acc[m][1][rr]) + (acc[m][2][rr] + acc[m][3][rr]);
            s += __shfl_xor(s, 1, 64);
            s += __shfl_xor(s, 2, 64);
            s += __shfl_xor(s, 4, 64);
            s += __shfl_xor(s, 8, 64);
            if ((lane & 15) == 0) {
                char* prow = Sb + (size_t)(tr + wrow + m * 16 + r0 + rr) * SROWB;
                ((float*)prow)[tj * 4 + (wid & 3)] = s;
            }
        }
    }

    if (ti != tj) {
        // mirror E writes: E[col][row] — 4 consecutive rows pack into one 8B store
#pragma unroll
        for (int m = 0; m < 8; ++m) {
#pragma unroll
            for (int n = 0; n < 4; ++n) {
                half4 h;
#pragma unroll
                for (int rr = 0; rr < 4; ++rr) h[rr] = (_Float16)acc[m][n][rr];
                char* mb = Sb + (size_t)(tc + wcol + n * 16 + c0) * SROWB + 4096
                              + (size_t)(tr + wrow + m * 16 + r0) * 2;
                *(half4*)mb = h;
            }
        }
        // mirror row sums = column sums over 64-row blocks (m 0..3 and m 4..7)
#pragma unroll
        for (int n = 0; n < 4; ++n) {
            float s0 = 0.0f, s1 = 0.0f;
#pragma unroll
            for (int m = 0; m < 4; ++m)
#pragma unroll
                for (int rr = 0; rr < 4; ++rr) s0 += acc[m][n][rr];
#pragma unroll
            for (int m = 4; m < 8; ++m)
#pragma unroll
                for (int rr = 0; rr < 4; ++rr) s1 += acc[m][n][rr];
            s0 += __shfl_xor(s0, 16, 64); s0 += __shfl_xor(s0, 32, 64);
            s1 += __shfl_xor(s1, 16, 64); s1 += __shfl_xor(s1, 32, 64);
            if (lane < 16) {
                char* prow = Sb + (size_t)(tc + wcol + n * 16 + lane) * SROWB;
                ((float*)prow)[ti * 4 + (wid >> 2) * 2 + 0] = s0;
                ((float*)prow)[ti * 4 + (wid >> 2) * 2 + 1] = s1;
            }
        }
    }
}

// ---------- kernel 3: normalize each row in place ----------
__global__ __launch_bounds__(256) void normalize_rows(char* sc) {
    const int row  = blockIdx.x * 4 + (threadIdx.x >> 6);
    const int lane = threadIdx.x & 63;
    char* rowc = sc + (size_t)row * SROWB;
    const _Float16* e = (const _Float16*)(rowc + 4096);
    float* s = (float*)rowc;

    float p = (lane < PARTS) ? ((const float*)rowc)[lane] : 0.0f;
#pragma unroll
    for (int o = 32; o > 0; o >>= 1) p += __shfl_xor(p, o, 64);
    const float inv = 1.0f / p;

    half8 v[4];
#pragma unroll
    for (int c = 0; c < 4; ++c)
        v[c] = *(const half8*)(e + c * 512 + lane * 8);

#pragma unroll
    for (int c = 0; c < 4; ++c) {
        float4 f0, f1;
        f0.x = (float)v[c][0] * inv; f0.y = (float)v[c][1] * inv;
        f0.z = (float)v[c][2] * inv; f0.w = (float)v[c][3] * inv;
        f1.x = (float)v[c][4] * inv; f1.y = (float)v[c][5] * inv;
        f1.z = (float)v[c][6] * inv; f1.w = (float)v[c][7] * inv;
        *(float4*)(s + c * 512 + lane * 8)     = f0;
        *(float4*)(s + c * 512 + lane * 8 + 4) = f1;
    }
}

// ---------- launcher ----------
extern "C" void kernel_launch(void* const* d_in, const int* in_sizes, int n_in,
                              void* d_out, int out_size, void* d_ws, size_t ws_size,
                              hipStream_t stream) {
    const float* X = (const float*)d_in[0];
    char*  sc  = (char*)d_out + NIN * 4;

    cvt_packed<<<NIN / (256 * 8), 256, 0, stream>>>(X, sc);
    gemm_sym7<<<288, 512, 0, stream>>>(sc, (const f32x4*)X, (f32x4*)d_out);
    normalize_rows<<<(B_ * S_) / 4, 256, 0, stream>>>(sc);
}

// Round 12
// 135.307 us; speedup vs baseline: 1.0809x; 1.0809x over previous
//
#include <hip/hip_runtime.h>

typedef unsigned short ushort_t;
using short8 = __attribute__((ext_vector_type(8))) short;
using half4  = __attribute__((ext_vector_type(4))) _Float16;
using half8  = __attribute__((ext_vector_type(8))) _Float16;
using f32x4  = __attribute__((ext_vector_type(4))) float;

#define AS1 __attribute__((address_space(1)))
#define AS3 __attribute__((address_space(3)))

// Problem sizes (fixed)
#define B_   8
#define S_   2048
#define D_   1024
#define NIN  (8UL * 2048UL * 1024UL)
#define PARTS 32
#define SROWB 8192UL
#define BATCHB (2048UL * SROWB)

// Per-score-row layout during the pipeline:
//   [0,128)     : 32 f32 partial row sums   (gemm -> normalize)
//   [2048,4096) : bf16 X row                (cvt -> gemm)
//   [4096,8192) : f16 E row = exp(logits)   (gemm -> normalize)
// normalize overwrites the whole row with final f32 scores.
// The exact f32 input copy streams through the gemm's idle VMEM slots.

__device__ __forceinline__ ushort_t f2bf(float f) {
    unsigned u = __float_as_uint(f);
    u += 0x7FFFu + ((u >> 16) & 1u);
    return (ushort_t)(u >> 16);
}

// ---------- kernel 1: f32 X -> parked bf16 ----------
__global__ __launch_bounds__(256) void cvt_packed(const float* __restrict__ in,
                                                  char* sc) {
    size_t g = ((size_t)blockIdx.x * 256 + threadIdx.x) * 8;
    const f32x4* p = (const f32x4*)(in + g);
    f32x4 a = p[0], c = p[1];
    short8 r;
    r[0] = (short)f2bf(a.x); r[1] = (short)f2bf(a.y);
    r[2] = (short)f2bf(a.z); r[3] = (short)f2bf(a.w);
    r[4] = (short)f2bf(c.x); r[5] = (short)f2bf(c.y);
    r[6] = (short)f2bf(c.z); r[7] = (short)f2bf(c.w);
    size_t xrow = g >> 10;
    size_t col  = g & 1023;
    char* dst = sc + xrow * SROWB + 2048 + col * 2;
    *(short8*)dst = r;
}

// ---------- kernel 2: symmetric GEMM 128x128, ring-4 BK=32, 1 barrier/phase ----------
__global__ __launch_bounds__(256, 2) void gemm_sym8(char* sc,
                                                    const f32x4* xin,
                                                    f32x4* xout) {
    // 4-slice ring per matrix: 4 x 8KB each => 64KB total LDS
    __shared__ __align__(16) ushort_t sA[4][128 * 32];
    __shared__ __align__(16) ushort_t sB[4][128 * 32];

    const int lin = blockIdx.x;
    // bijective XCD swizzle: 1088 = 8 * 136
    const int wg  = (lin & 7) * 136 + (lin >> 3);
    const int b   = wg / 136;
    int rem = wg % 136, ti = 0;
    while (rem >= 16 - ti) { rem -= 16 - ti; ++ti; }
    const int tj = ti + rem;
    const int tr = ti * 128, tc = tj * 128;

    char* Sb = sc + (size_t)b * BATCHB;

    const int tid  = threadIdx.x;
    const int lane = tid & 63;
    const int wid  = tid >> 6;
    const int wr = (wid >> 1) * 64;
    const int wc = (wid & 1) * 64;

    // embedded copy: blocks lin<512, 1 float4 ld+st per phase, 32 phases
    const bool docopy = (lin < 512);
    const size_t cbase = (size_t)lin * 256 + tid;   // < 131072 when docopy

    f32x4 acc[4][4] = {};
    f32x4 creg;

    const int srow_s = tid >> 2;          // 0..63 (row within 64-row stripe)
    const int cd     = tid & 3;           // 16B chunk within 64B row
    const int rsel = lane & 15;
    const int g4   = lane >> 4;           // 0..3: K-quarter (chunk)

    // stage slice s (K cols s*32..s*32+31) into ring slot; 2 instrs per matrix
    auto stage = [&](int s, int slot) {
#pragma unroll
        for (int j = 0; j < 2; ++j) {
            const int row = j * 64 + srow_s;
            const int csw = (cd ^ ((row >> 1) & 3)) << 4;   // pre-swizzled source chunk
            __builtin_amdgcn_global_load_lds(
                (const AS1 void*)(Sb + (size_t)(tr + row) * SROWB + 2048 + (size_t)s * 64 + csw),
                (AS3 void*)((char*)&sA[slot][0] + j * 4096 + tid * 16), 16, 0, 0);
        }
#pragma unroll
        for (int j = 0; j < 2; ++j) {
            const int row = j * 64 + srow_s;
            const int csw = (cd ^ ((row >> 1) & 3)) << 4;
            __builtin_amdgcn_global_load_lds(
                (const AS1 void*)(Sb + (size_t)(tc + row) * SROWB + 2048 + (size_t)s * 64 + csw),
                (AS3 void*)((char*)&sB[slot][0] + j * 4096 + tid * 16), 16, 0, 0);
        }
    };

    short8 af[4], bfr[4];
    auto readfrags = [&](int slot) {
#pragma unroll
        for (int m = 0; m < 4; ++m) {
            const int row = wr + m * 16 + rsel;
            const int csw = (g4 ^ ((row >> 1) & 3)) << 4;
            af[m] = *(const short8*)((const char*)&sA[slot][0] + row * 64 + csw);
        }
#pragma unroll
        for (int n = 0; n < 4; ++n) {
            const int row = wc + n * 16 + rsel;
            const int csw = (g4 ^ ((row >> 1) & 3)) << 4;
            bfr[n] = *(const short8*)((const char*)&sB[slot][0] + row * 64 + csw);
        }
    };

    // prologue: stage slices 0,1,2 into slots 0,1,2
    stage(0, 0);
    stage(1, 1);
    stage(2, 2);

#pragma unroll
    for (int s = 0; s < 32; ++s) {
        // counted wait: guarantee stage(s) landed (issued at phase s-3 / prologue);
        // everything newer (2 later stage groups + copy tail) stays in flight.
        if (docopy) {
            if (s == 0)       asm volatile("s_waitcnt vmcnt(8)"  ::: "memory");
            else if (s == 1)  asm volatile("s_waitcnt vmcnt(9)"  ::: "memory");
            else if (s == 2)  asm volatile("s_waitcnt vmcnt(11)" ::: "memory");
            else if (s == 3)  asm volatile("s_waitcnt vmcnt(13)" ::: "memory");
            else if (s <= 29) asm volatile("s_waitcnt vmcnt(14)" ::: "memory");
            else if (s == 30) asm volatile("s_waitcnt vmcnt(10)" ::: "memory");
            else              asm volatile("s_waitcnt vmcnt(6)"  ::: "memory");
        } else {
            if (s <= 29)      asm volatile("s_waitcnt vmcnt(8)"  ::: "memory");
            else if (s == 30) asm volatile("s_waitcnt vmcnt(4)"  ::: "memory");
            else              asm volatile("s_waitcnt vmcnt(0)"  ::: "memory");
        }
        __builtin_amdgcn_s_barrier();   // all waves: slice s resident; slot (s+3)&3 free

        if (s + 3 < 32) stage(s + 3, (s + 3) & 3);   // overwrite slice s-1's slot

        if (docopy) {
            if (s > 0) xout[cbase + (size_t)(s - 1) * 131072] = creg;
            creg = xin[cbase + (size_t)s * 131072];
        }

        readfrags(s & 3);
        asm volatile("s_waitcnt lgkmcnt(0)" ::: "memory");
        __builtin_amdgcn_sched_barrier(0);

        __builtin_amdgcn_s_setprio(1);
#pragma unroll
        for (int m = 0; m < 4; ++m)
#pragma unroll
            for (int n = 0; n < 4; ++n)
                acc[m][n] = __builtin_amdgcn_mfma_f32_16x16x32_bf16(
                    af[m], bfr[n], acc[m][n], 0, 0, 0);
        __builtin_amdgcn_s_setprio(0);
    }

    if (docopy) xout[cbase + 31UL * 131072] = creg;

    // ---------------- epilogue (unchanged from R6) ----------------
    const float scale = 1.0f / 2048.0f;
    const int r0 = (lane >> 4) * 4;
    const int c0 = lane & 15;

#pragma unroll
    for (int m = 0; m < 4; ++m)
#pragma unroll
        for (int n = 0; n < 4; ++n)
#pragma unroll
            for (int rr = 0; rr < 4; ++rr)
                acc[m][n][rr] = __expf(acc[m][n][rr] * scale);

#pragma unroll
    for (int m = 0; m < 4; ++m) {
#pragma unroll
        for (int n = 0; n < 4; ++n) {
            char* dbase = Sb + (size_t)(tr + wr + m * 16 + r0) * SROWB + 4096
                             + (size_t)(tc + wc + n * 16 + c0) * 2;
#pragma unroll
            for (int rr = 0; rr < 4; ++rr)
                *(_Float16*)(dbase + (size_t)rr * SROWB) = (_Float16)acc[m][n][rr];
        }
    }

#pragma unroll
    for (int m = 0; m < 4; ++m) {
#pragma unroll
        for (int rr = 0; rr < 4; ++rr) {
            float s = (acc[m][0][rr] + acc[m][1][rr]) + (acc[m][2][rr] + acc[m][3][rr]);
            s += __shfl_xor(s, 1, 64);
            s += __shfl_xor(s, 2, 64);
            s += __shfl_xor(s, 4, 64);
            s += __shfl_xor(s, 8, 64);
            if ((lane & 15) == 0) {
                char* prow = Sb + (size_t)(tr + wr + m * 16 + r0 + rr) * SROWB;
                ((float*)prow)[tj * 2 + (wid & 1)] = s;
            }
        }
    }

    if (ti != tj) {
#pragma unroll
        for (int m = 0; m < 4; ++m) {
#pragma unroll
            for (int n = 0; n < 4; ++n) {
                half4 h;
#pragma unroll
                for (int rr = 0; rr < 4; ++rr) h[rr] = (_Float16)acc[m][n][rr];
                char* mb = Sb + (size_t)(tc + wc + n * 16 + c0) * SROWB + 4096
                              + (size_t)(tr + wr + m * 16 + r0) * 2;
                *(half4*)mb = h;
            }
        }
#pragma unroll
        for (int n = 0; n < 4; ++n) {
            float s = 0.0f;
#pragma unroll
            for (int m = 0; m < 4; ++m)
#pragma unroll
                for (int rr = 0; rr < 4; ++rr) s += acc[m][n][rr];
            s += __shfl_xor(s, 16, 64);
            s += __shfl_xor(s, 32, 64);
            if (lane < 16) {
                char* prow = Sb + (size_t)(tc + wc + n * 16 + lane) * SROWB;
                ((float*)prow)[ti * 2 + (wid >> 1)] = s;
            }
        }
    }
}

// ---------- kernel 3: normalize each row in place ----------
__global__ __launch_bounds__(256) void normalize_rows(char* sc) {
    const int row  = blockIdx.x * 4 + (threadIdx.x >> 6);
    const int lane = threadIdx.x & 63;
    char* rowc = sc + (size_t)row * SROWB;
    const _Float16* e = (const _Float16*)(rowc + 4096);
    float* s = (float*)rowc;

    float p = (lane < PARTS) ? ((const float*)rowc)[lane] : 0.0f;
#pragma unroll
    for (int o = 32; o > 0; o >>= 1) p += __shfl_xor(p, o, 64);
    const float inv = 1.0f / p;

    half8 v[4];
#pragma unroll
    for (int c = 0; c < 4; ++c)
        v[c] = *(const half8*)(e + c * 512 + lane * 8);

#pragma unroll
    for (int c = 0; c < 4; ++c) {
        float4 f0, f1;
        f0.x = (float)v[c][0] * inv; f0.y = (float)v[c][1] * inv;
        f0.z = (float)v[c][2] * inv; f0.w = (float)v[c][3] * inv;
        f1.x = (float)v[c][4] * inv; f1.y = (float)v[c][5] * inv;
        f1.z = (float)v[c][6] * inv; f1.w = (float)v[c][7] * inv;
        *(float4*)(s + c * 512 + lane * 8)     = f0;
        *(float4*)(s + c * 512 + lane * 8 + 4) = f1;
    }
}

// ---------- launcher ----------
extern "C" void kernel_launch(void* const* d_in, const int* in_sizes, int n_in,
                              void* d_out, int out_size, void* d_ws, size_t ws_size,
                              hipStream_t stream) {
    const float* X = (const float*)d_in[0];
    char*  sc  = (char*)d_out + NIN * 4;

    cvt_packed<<<NIN / (256 * 8), 256, 0, stream>>>(X, sc);
    gemm_sym8<<<1088, 256, 0, stream>>>(sc, (const f32x4*)X, (f32x4*)d_out);
    normalize_rows<<<(B_ * S_) / 4, 256, 0, stream>>>(sc);
}